// Round 10
// baseline (632.377 us; speedup 1.0000x reference)
//
#include <hip/hip_runtime.h>

// GPT-2 attention block for MI355X (gfx950), bf16 MFMA everywhere, fp32 accum.
// Outputs: [attn_output 2*2048*1024 f32][attn_weights 2*16*2048*2048 f32]
// R10: fused attn (R3 structure) + T14 reg-prefetch staging in both phases.

typedef __bf16 bf16_t;
typedef bf16_t bf16x8 __attribute__((ext_vector_type(8)));
typedef float f32x4 __attribute__((ext_vector_type(4)));
typedef unsigned short ushort8 __attribute__((ext_vector_type(8)));
typedef unsigned short ushort4v __attribute__((ext_vector_type(4)));

#define SEQ 2048
#define DMODEL 1024
#define MTOT 4096  // B*SEQ

#define AS1 __attribute__((address_space(1)))
#define AS3 __attribute__((address_space(3)))

__device__ __forceinline__ unsigned short f2bf(float f) {
  return __builtin_bit_cast(unsigned short, (bf16_t)f);
}
__device__ __forceinline__ float bf2f(unsigned short u) {
  return __builtin_bit_cast(float, (unsigned)u << 16);
}
__device__ __forceinline__ bf16x8 ldb8(const unsigned short* p) {
  return __builtin_bit_cast(bf16x8, *(const ushort8*)p);
}
__device__ __forceinline__ f32x4 mfma16(bf16x8 a, bf16x8 b, f32x4 c) {
  return __builtin_amdgcn_mfma_f32_16x16x32_bf16(a, b, c, 0, 0, 0);
}
// async global->LDS, 16 bytes per lane (GEMM staging).
__device__ __forceinline__ void gload16(const unsigned short* g, unsigned short* l) {
  __builtin_amdgcn_global_load_lds((AS1 const void*)g, (AS3 void*)l, 16, 0, 0);
}

// ---------- cast f32 -> bf16 bits ----------
__global__ __launch_bounds__(256) void cast_kernel(const float* __restrict__ in,
                                                   unsigned short* __restrict__ out) {
  int i = blockIdx.x * 256 + threadIdx.x;
  float4 v = ((const float4*)in)[i];
  ushort4v o;
  o[0] = f2bf(v.x); o[1] = f2bf(v.y); o[2] = f2bf(v.z); o[3] = f2bf(v.w);
  ((ushort4v*)out)[i] = o;
}

// ---------- transpose + cast: in f32 [R][C] -> out bf16 [C][R] ----------
__global__ __launch_bounds__(256) void transpose_cast_kernel(const float* __restrict__ in,
                                                             unsigned short* __restrict__ out,
                                                             int R, int C) {
  __shared__ float tile[32][33];
  int c0 = blockIdx.x * 32, r0 = blockIdx.y * 32;
  int tx = threadIdx.x & 31, ty = threadIdx.x >> 5;
#pragma unroll
  for (int i = 0; i < 4; ++i)
    tile[ty + i * 8][tx] = in[(size_t)(r0 + ty + i * 8) * C + c0 + tx];
  __syncthreads();
#pragma unroll
  for (int i = 0; i < 4; ++i)
    out[(size_t)(c0 + ty + i * 8) * R + r0 + tx] = f2bf(tile[tx][ty + i * 8]);
}

// ---------- m97-structure bf16 GEMM: C[M][N] = A[M][K]*BT[N][K]^T + bias ----------
template <int EPI>
__global__ __launch_bounds__(256) void gemm128(
    const unsigned short* __restrict__ A, const unsigned short* __restrict__ BT,
    const float* __restrict__ bias, float* __restrict__ outF,
    unsigned short* __restrict__ qws, unsigned short* __restrict__ kws,
    unsigned short* __restrict__ vws, int M, int N, int K) {
  __shared__ unsigned short Alds[128 * 32];
  __shared__ unsigned short Blds[128 * 32];
  int m0 = blockIdx.x * 128, n0 = blockIdx.y * 128;
  int t = threadIdx.x;
  int l = t & 63, j = l & 15, g = l >> 4;
  int w = t >> 6, wr = w >> 1, wc = w & 1;

  f32x4 acc[4][4];
#pragma unroll
  for (int mi = 0; mi < 4; ++mi)
#pragma unroll
    for (int st = 0; st < 4; ++st)
#pragma unroll
      for (int r = 0; r < 4; ++r) acc[mi][st][r] = 0.f;

  int srow = t >> 2;          // 0..63
  int scol = (t & 3) * 8;     // 0,8,16,24
  const unsigned short* aB0 = A + (size_t)(m0 + srow) * K + scol;
  const unsigned short* aB1 = aB0 + (size_t)64 * K;
  const unsigned short* bB0 = BT + (size_t)(n0 + srow) * K + scol;
  const unsigned short* bB1 = bB0 + (size_t)64 * K;
  unsigned short* aL0 = &Alds[srow * 32 + scol];
  unsigned short* aL1 = aL0 + 64 * 32;
  unsigned short* bL0 = &Blds[srow * 32 + scol];
  unsigned short* bL1 = bL0 + 64 * 32;

  for (int k0 = 0; k0 < K; k0 += 32) {
    __syncthreads();
    gload16(aB0 + k0, aL0);
    gload16(aB1 + k0, aL1);
    gload16(bB0 + k0, bL0);
    gload16(bB1 + k0, bL1);
    __syncthreads();
    bf16x8 af[4], bfr[4];
#pragma unroll
    for (int mi = 0; mi < 4; ++mi) af[mi] = ldb8(&Alds[(wr * 64 + mi * 16 + j) * 32 + g * 8]);
#pragma unroll
    for (int st = 0; st < 4; ++st) bfr[st] = ldb8(&Blds[(wc * 64 + st * 16 + j) * 32 + g * 8]);
#pragma unroll
    for (int mi = 0; mi < 4; ++mi)
#pragma unroll
      for (int st = 0; st < 4; ++st) acc[mi][st] = mfma16(af[mi], bfr[st], acc[mi][st]);
  }

#pragma unroll
  for (int st = 0; st < 4; ++st) {
    int n = n0 + wc * 64 + st * 16 + j;
    float bv = bias[n];
#pragma unroll
    for (int mi = 0; mi < 4; ++mi)
#pragma unroll
      for (int r = 0; r < 4; ++r) {
        int m = m0 + wr * 64 + mi * 16 + g * 4 + r;
        float val = acc[mi][st][r] + bv;
        if (EPI == 1) {
          outF[(size_t)m * N + n] = val;
        } else {
          int region = n >> 10;          // 0=q 1=k 2=v
          int h = (n & 1023) >> 6;
          int d = n & 63;
          int bb = m >> 11, s = m & 2047;
          int bh = bb * 16 + h;
          if (region == 0) qws[(((size_t)bh) * SEQ + s) * 64 + d] = f2bf(val * 0.125f);
          else if (region == 1) kws[(((size_t)bh) * SEQ + s) * 64 + d] = f2bf(val);
          else vws[(((size_t)bh) * 64 + d) * SEQ + s] = f2bf(val);  // transposed
        }
      }
  }
}

// ---------- fused causal attention (R3 structure + T14 reg-prefetch) ----------
// grid (32 q-tiles heavy-first, 32 b*h); 4 waves/block, wave owns 16 q-rows.
// Phase 1: l = sum exp(s). Phase 2: P=exp(s)/l (store f32) + PV.
// Staging: next tile's K/V global loads issued right after the ready-barrier,
// held in regs, ds_written at the top of the next iteration.
__global__ __launch_bounds__(256) void attn_kernel(
    const unsigned short* __restrict__ qg, const unsigned short* __restrict__ kg,
    const unsigned short* __restrict__ vg, float* __restrict__ outw,
    unsigned short* __restrict__ ointer) {
  __shared__ unsigned short Klds[64][72];       // [key][d]
  __shared__ unsigned short Vlds[64][72];       // [d][key] (transposed in global)
  __shared__ unsigned short Plds[4][16 * 72];   // per-wave P tile, bf16

  int qt = 31 - blockIdx.x;             // heavy tiles first
  int bh = blockIdx.y;
  int b = bh >> 4, h = bh & 15;
  int t = threadIdx.x;
  int w = t >> 6, l = t & 63, j = l & 15, g = l >> 4;

  const unsigned short* qb = qg + (size_t)bh * SEQ * 64;
  const unsigned short* kb = kg + (size_t)bh * SEQ * 64;
  const unsigned short* vb = vg + (size_t)bh * SEQ * 64;  // [64][SEQ]
  float* outrow = outw + (size_t)bh * SEQ * SEQ;

  int qr_a = qt * 64 + w * 16 + j;
  bf16x8 qa0 = ldb8(&qb[(size_t)qr_a * 64 + g * 8]);
  bf16x8 qa1 = ldb8(&qb[(size_t)qr_a * 64 + 32 + g * 8]);

  int qrow0 = qt * 64 + w * 16 + g * 4;  // D rows = qrow0 + r

  int skey = t >> 2;        // staging row (key for K, d for V)
  int sc = (t & 3) * 8;     // staging col chunk

  float lpart[4] = {0.f, 0.f, 0.f, 0.f};

  // ===== phase 1: per-lane partial sums of exp(s) =====
  ushort8 kr0 = *(const ushort8*)&kb[(size_t)skey * 64 + sc];
  ushort8 kr1 = *(const ushort8*)&kb[(size_t)skey * 64 + sc + 32];
  for (int kt = 0; kt <= qt; ++kt) {
    __syncthreads();  // prev tile fully consumed
    *(ushort8*)&Klds[skey][sc] = kr0;
    *(ushort8*)&Klds[skey][sc + 32] = kr1;
    __syncthreads();  // tile ready
    if (kt < qt) {    // T14: issue next-tile loads now; land under compute
      const unsigned short* nk = &kb[(size_t)((kt + 1) * 64 + skey) * 64];
      kr0 = *(const ushort8*)&nk[sc];
      kr1 = *(const ushort8*)&nk[sc + 32];
    }
    f32x4 sacc[4];
#pragma unroll
    for (int st = 0; st < 4; ++st)
#pragma unroll
      for (int r = 0; r < 4; ++r) sacc[st][r] = 0.f;
#pragma unroll
    for (int st = 0; st < 4; ++st) {
      bf16x8 kf0 = ldb8(&Klds[st * 16 + j][g * 8]);
      bf16x8 kf1 = ldb8(&Klds[st * 16 + j][32 + g * 8]);
      sacc[st] = mfma16(qa0, kf0, sacc[st]);
      sacc[st] = mfma16(qa1, kf1, sacc[st]);
    }
    bool diag = (kt == qt);
#pragma unroll
    for (int r = 0; r < 4; ++r) {
#pragma unroll
      for (int st = 0; st < 4; ++st) {
        float p = __expf(sacc[st][r]);
        if (diag) {
          int kc = kt * 64 + st * 16 + j;
          p = (kc > qrow0 + r) ? 0.f : p;
        }
        lpart[r] += p;
      }
    }
  }

  // deferred reduce over the 16 j-lanes
  float linv[4];
#pragma unroll
  for (int r = 0; r < 4; ++r) {
    float sum = lpart[r];
#pragma unroll
    for (int o = 1; o < 16; o <<= 1) sum += __shfl_xor(sum, o);
    linv[r] = 1.f / sum;
  }

  f32x4 oacc[4];
#pragma unroll
  for (int st = 0; st < 4; ++st)
#pragma unroll
    for (int r = 0; r < 4; ++r) oacc[st][r] = 0.f;

  int prow = l >> 2;        // P writeback row 0..15
  int pch = l & 3;          // chunk base (8 keys per chunk)

  // ===== phase 2: P write + PV =====
  kr0 = *(const ushort8*)&kb[(size_t)skey * 64 + sc];
  kr1 = *(const ushort8*)&kb[(size_t)skey * 64 + sc + 32];
  ushort8 vr0 = *(const ushort8*)&vb[(size_t)skey * SEQ + sc];
  ushort8 vr1 = *(const ushort8*)&vb[(size_t)skey * SEQ + sc + 32];
  for (int kt = 0; kt <= qt; ++kt) {
    __syncthreads();
    *(ushort8*)&Klds[skey][sc] = kr0;
    *(ushort8*)&Klds[skey][sc + 32] = kr1;
    *(ushort8*)&Vlds[skey][sc] = vr0;
    *(ushort8*)&Vlds[skey][sc + 32] = vr1;
    __syncthreads();
    if (kt < qt) {    // T14 prefetch for kt+1
      const unsigned short* nk = &kb[(size_t)((kt + 1) * 64 + skey) * 64];
      const unsigned short* nv = &vb[(size_t)skey * SEQ + (kt + 1) * 64];
      kr0 = *(const ushort8*)&nk[sc];
      kr1 = *(const ushort8*)&nk[sc + 32];
      vr0 = *(const ushort8*)&nv[sc];
      vr1 = *(const ushort8*)&nv[sc + 32];
    }
    f32x4 sacc[4];
#pragma unroll
    for (int st = 0; st < 4; ++st)
#pragma unroll
      for (int r = 0; r < 4; ++r) sacc[st][r] = 0.f;
#pragma unroll
    for (int st = 0; st < 4; ++st) {
      bf16x8 kf0 = ldb8(&Klds[st * 16 + j][g * 8]);
      bf16x8 kf1 = ldb8(&Klds[st * 16 + j][32 + g * 8]);
      sacc[st] = mfma16(qa0, kf0, sacc[st]);
      sacc[st] = mfma16(qa1, kf1, sacc[st]);
    }
    bool diag = (kt == qt);
#pragma unroll
    for (int st = 0; st < 4; ++st)
#pragma unroll
      for (int r = 0; r < 4; ++r) {
        int kc = kt * 64 + st * 16 + j;
        float p = __expf(sacc[st][r]) * linv[r];
        if (diag) p = (kc > qrow0 + r) ? 0.f : p;
        Plds[w][(g * 4 + r) * 72 + st * 16 + j] = f2bf(p);
      }
    // vectorized P global write (bf16 -> f32); Plds[w] wave-private, lgkm-ordered
#pragma unroll
    for (int it = 0; it < 2; ++it) {
      int ch = pch + it * 4;
      ushort8 pv = *(const ushort8*)&Plds[w][prow * 72 + ch * 8];
      float4 f0, f1;
      f0.x = bf2f(pv[0]); f0.y = bf2f(pv[1]); f0.z = bf2f(pv[2]); f0.w = bf2f(pv[3]);
      f1.x = bf2f(pv[4]); f1.y = bf2f(pv[5]); f1.z = bf2f(pv[6]); f1.w = bf2f(pv[7]);
      float* dst = &outrow[(size_t)(qt * 64 + w * 16 + prow) * SEQ + kt * 64 + ch * 8];
      ((float4*)dst)[0] = f0;
      ((float4*)dst)[1] = f1;
    }
    bf16x8 pa0 = ldb8(&Plds[w][j * 72 + g * 8]);
    bf16x8 pa1 = ldb8(&Plds[w][j * 72 + 32 + g * 8]);
#pragma unroll
    for (int st = 0; st < 4; ++st) {
      bf16x8 vf0 = ldb8(&Vlds[st * 16 + j][g * 8]);
      bf16x8 vf1 = ldb8(&Vlds[st * 16 + j][32 + g * 8]);
      oacc[st] = mfma16(pa0, vf0, oacc[st]);
      oacc[st] = mfma16(pa1, vf1, oacc[st]);
    }
  }

  // write O to [B][SEQ][DMODEL] bf16 intermediate
#pragma unroll
  for (int st = 0; st < 4; ++st)
#pragma unroll
    for (int r = 0; r < 4; ++r) {
      int qrow = qrow0 + r;
      int d = st * 16 + j;
      ointer[((size_t)b * SEQ + qrow) * DMODEL + h * 64 + d] = f2bf(oacc[st][r]);
    }

  // fully-masked tiles: exact zeros (barrier-free tail)
  {
    int row = qt * 64 + w * 16 + (l >> 2);
    int cc = (l & 3) * 16;
    float4 z = make_float4(0.f, 0.f, 0.f, 0.f);
    for (int kt = qt + 1; kt < SEQ / 64; ++kt) {
      float4* zp = (float4*)&outrow[(size_t)row * SEQ + kt * 64 + cc];
      zp[0] = z; zp[1] = z; zp[2] = z; zp[3] = z;
    }
  }
}

extern "C" void kernel_launch(void* const* d_in, const int* in_sizes, int n_in,
                              void* d_out, int out_size, void* d_ws, size_t ws_size,
                              hipStream_t stream) {
  const float* hidden = (const float*)d_in[0];   // [2,2048,1024]
  const float* w_attn = (const float*)d_in[1];   // [1024,3072]
  const float* b_attn = (const float*)d_in[2];   // [3072]
  const float* w_proj = (const float*)d_in[3];   // [1024,1024]
  const float* b_proj = (const float*)d_in[4];   // [1024]

  float* out_attn = (float*)d_out;                          // 4,194,304 f32
  float* out_w = out_attn + (size_t)MTOT * DMODEL;          // 134,217,728 f32

  char* ws = (char*)d_ws;
  unsigned short* hbf = (unsigned short*)(ws);              // [4096][1024] bf16; later reused as attn O
  unsigned short* w1T = (unsigned short*)(ws + 8388608);    // [3072][1024] bf16
  unsigned short* w2T = (unsigned short*)(ws + 14680064);   // [1024][1024] bf16
  unsigned short* qws = (unsigned short*)(ws + 16777216);   // [32][2048][64] bf16 (pre-scaled 1/8)
  unsigned short* kws = (unsigned short*)(ws + 25165824);   // [32][2048][64]
  unsigned short* vws = (unsigned short*)(ws + 33554432);   // [32][64][2048] (transposed)

  cast_kernel<<<4096, 256, 0, stream>>>(hidden, hbf);
  transpose_cast_kernel<<<dim3(96, 32), 256, 0, stream>>>(w_attn, w1T, 1024, 3072);
  transpose_cast_kernel<<<dim3(32, 32), 256, 0, stream>>>(w_proj, w2T, 1024, 1024);
  gemm128<0><<<dim3(32, 24), 256, 0, stream>>>(hbf, w1T, b_attn, nullptr, qws, kws, vws,
                                               MTOT, 3 * DMODEL, DMODEL);
  attn_kernel<<<dim3(32, 32), 256, 0, stream>>>(qws, kws, vws, out_w, hbf);
  gemm128<1><<<dim3(32, 8), 256, 0, stream>>>(hbf, w2T, b_proj, out_attn, nullptr, nullptr,
                                              nullptr, MTOT, DMODEL, DMODEL);
}

// Round 11
// 271.453 us; speedup vs baseline: 2.3296x; 2.3296x over previous
//
#include <hip/hip_runtime.h>

// GPT-2 attention block for MI355X (gfx950), bf16 MFMA everywhere, fp32 accum.
// Outputs: [attn_output 2*2048*1024 f32][attn_weights 2*16*2048*2048 f32]
// R11 = exact R3 structure (best: 273us) + diagonal qt remap for per-CU balance.

typedef __bf16 bf16_t;
typedef bf16_t bf16x8 __attribute__((ext_vector_type(8)));
typedef float f32x4 __attribute__((ext_vector_type(4)));
typedef unsigned short ushort8 __attribute__((ext_vector_type(8)));
typedef unsigned short ushort4v __attribute__((ext_vector_type(4)));

#define SEQ 2048
#define DMODEL 1024
#define MTOT 4096  // B*SEQ

#define AS1 __attribute__((address_space(1)))
#define AS3 __attribute__((address_space(3)))

__device__ __forceinline__ unsigned short f2bf(float f) {
  return __builtin_bit_cast(unsigned short, (bf16_t)f);
}
__device__ __forceinline__ float bf2f(unsigned short u) {
  return __builtin_bit_cast(float, (unsigned)u << 16);
}
__device__ __forceinline__ bf16x8 ldb8(const unsigned short* p) {
  return __builtin_bit_cast(bf16x8, *(const ushort8*)p);
}
__device__ __forceinline__ f32x4 mfma16(bf16x8 a, bf16x8 b, f32x4 c) {
  return __builtin_amdgcn_mfma_f32_16x16x32_bf16(a, b, c, 0, 0, 0);
}
// async global->LDS, 16 bytes per lane. LDS dest must be wave-uniform-base + lane*16.
__device__ __forceinline__ void gload16(const unsigned short* g, unsigned short* l) {
  __builtin_amdgcn_global_load_lds((AS1 const void*)g, (AS3 void*)l, 16, 0, 0);
}

// ---------- cast f32 -> bf16 bits ----------
__global__ __launch_bounds__(256) void cast_kernel(const float* __restrict__ in,
                                                   unsigned short* __restrict__ out) {
  int i = blockIdx.x * 256 + threadIdx.x;
  float4 v = ((const float4*)in)[i];
  ushort4v o;
  o[0] = f2bf(v.x); o[1] = f2bf(v.y); o[2] = f2bf(v.z); o[3] = f2bf(v.w);
  ((ushort4v*)out)[i] = o;
}

// ---------- transpose + cast: in f32 [R][C] -> out bf16 [C][R] ----------
__global__ __launch_bounds__(256) void transpose_cast_kernel(const float* __restrict__ in,
                                                             unsigned short* __restrict__ out,
                                                             int R, int C) {
  __shared__ float tile[32][33];
  int c0 = blockIdx.x * 32, r0 = blockIdx.y * 32;
  int tx = threadIdx.x & 31, ty = threadIdx.x >> 5;
#pragma unroll
  for (int i = 0; i < 4; ++i)
    tile[ty + i * 8][tx] = in[(size_t)(r0 + ty + i * 8) * C + c0 + tx];
  __syncthreads();
#pragma unroll
  for (int i = 0; i < 4; ++i)
    out[(size_t)(c0 + ty + i * 8) * R + r0 + tx] = f2bf(tile[tx][ty + i * 8]);
}

// ---------- m97-structure bf16 GEMM: C[M][N] = A[M][K]*BT[N][K]^T + bias ----------
template <int EPI>
__global__ __launch_bounds__(256) void gemm128(
    const unsigned short* __restrict__ A, const unsigned short* __restrict__ BT,
    const float* __restrict__ bias, float* __restrict__ outF,
    unsigned short* __restrict__ qws, unsigned short* __restrict__ kws,
    unsigned short* __restrict__ vws, int M, int N, int K) {
  __shared__ unsigned short Alds[128 * 32];
  __shared__ unsigned short Blds[128 * 32];
  int m0 = blockIdx.x * 128, n0 = blockIdx.y * 128;
  int t = threadIdx.x;
  int l = t & 63, j = l & 15, g = l >> 4;
  int w = t >> 6, wr = w >> 1, wc = w & 1;

  f32x4 acc[4][4];
#pragma unroll
  for (int mi = 0; mi < 4; ++mi)
#pragma unroll
    for (int st = 0; st < 4; ++st)
#pragma unroll
      for (int r = 0; r < 4; ++r) acc[mi][st][r] = 0.f;

  int srow = t >> 2;          // 0..63
  int scol = (t & 3) * 8;     // 0,8,16,24
  const unsigned short* aB0 = A + (size_t)(m0 + srow) * K + scol;
  const unsigned short* aB1 = aB0 + (size_t)64 * K;
  const unsigned short* bB0 = BT + (size_t)(n0 + srow) * K + scol;
  const unsigned short* bB1 = bB0 + (size_t)64 * K;
  unsigned short* aL0 = &Alds[srow * 32 + scol];
  unsigned short* aL1 = aL0 + 64 * 32;
  unsigned short* bL0 = &Blds[srow * 32 + scol];
  unsigned short* bL1 = bL0 + 64 * 32;

  for (int k0 = 0; k0 < K; k0 += 32) {
    __syncthreads();
    gload16(aB0 + k0, aL0);
    gload16(aB1 + k0, aL1);
    gload16(bB0 + k0, bL0);
    gload16(bB1 + k0, bL1);
    __syncthreads();
    bf16x8 af[4], bfr[4];
#pragma unroll
    for (int mi = 0; mi < 4; ++mi) af[mi] = ldb8(&Alds[(wr * 64 + mi * 16 + j) * 32 + g * 8]);
#pragma unroll
    for (int st = 0; st < 4; ++st) bfr[st] = ldb8(&Blds[(wc * 64 + st * 16 + j) * 32 + g * 8]);
#pragma unroll
    for (int mi = 0; mi < 4; ++mi)
#pragma unroll
      for (int st = 0; st < 4; ++st) acc[mi][st] = mfma16(af[mi], bfr[st], acc[mi][st]);
  }

#pragma unroll
  for (int st = 0; st < 4; ++st) {
    int n = n0 + wc * 64 + st * 16 + j;
    float bv = bias[n];
#pragma unroll
    for (int mi = 0; mi < 4; ++mi)
#pragma unroll
      for (int r = 0; r < 4; ++r) {
        int m = m0 + wr * 64 + mi * 16 + g * 4 + r;
        float val = acc[mi][st][r] + bv;
        if (EPI == 1) {
          outF[(size_t)m * N + n] = val;
        } else {
          int region = n >> 10;          // 0=q 1=k 2=v
          int h = (n & 1023) >> 6;
          int d = n & 63;
          int bb = m >> 11, s = m & 2047;
          int bh = bb * 16 + h;
          if (region == 0) qws[(((size_t)bh) * SEQ + s) * 64 + d] = f2bf(val * 0.125f);
          else if (region == 1) kws[(((size_t)bh) * SEQ + s) * 64 + d] = f2bf(val);
          else vws[(((size_t)bh) * 64 + d) * SEQ + s] = f2bf(val);  // transposed
        }
      }
  }
}

// ---------- fused causal attention (R3 structure, diagonal qt remap) ----------
// grid (32 q-tiles, 32 b*h); 4 waves/block, wave owns 16 q-rows.
// qt = (bx + by) & 31: bijective per bh; blocks co-resident on a CU (periodic
// in blockIdx) get different qt -> per-CU tile-iteration counts equalize (~66).
__global__ __launch_bounds__(256) void attn_kernel(
    const unsigned short* __restrict__ qg, const unsigned short* __restrict__ kg,
    const unsigned short* __restrict__ vg, float* __restrict__ outw,
    unsigned short* __restrict__ ointer) {
  __shared__ unsigned short Klds[64][72];       // [key][d]
  __shared__ unsigned short Vlds[64][72];       // [d][key] (transposed in global)
  __shared__ unsigned short Plds[4][16][72];    // per-wave P tile [qrow][key], bf16

  int qt = (blockIdx.x + blockIdx.y) & 31;      // diagonal remap (R11 change)
  int bh = blockIdx.y;
  int b = bh >> 4, h = bh & 15;
  int t = threadIdx.x;
  int w = t >> 6, l = t & 63, j = l & 15, g = l >> 4;

  const unsigned short* qb = qg + (size_t)bh * SEQ * 64;
  const unsigned short* kb = kg + (size_t)bh * SEQ * 64;
  const unsigned short* vb = vg + (size_t)bh * SEQ * 64;  // [64][SEQ]
  float* outrow = outw + (size_t)bh * SEQ * SEQ;

  int qr_a = qt * 64 + w * 16 + j;  // A-fragment row
  bf16x8 qa0 = ldb8(&qb[(size_t)qr_a * 64 + g * 8]);
  bf16x8 qa1 = ldb8(&qb[(size_t)qr_a * 64 + 32 + g * 8]);

  int qrow0 = qt * 64 + w * 16 + g * 4;  // D rows = qrow0 + r

  float lpart[4] = {0.f, 0.f, 0.f, 0.f};

  int skey = t >> 2;        // staging row (key for K, d for V)
  int sc = (t & 3) * 8;     // staging col chunk

  // ---- phase 1: per-lane partial sums of exp(s) ----
  for (int kt = 0; kt <= qt; ++kt) {
    __syncthreads();
    {
      const unsigned short* src = &kb[(size_t)(kt * 64 + skey) * 64];
      *(ushort8*)&Klds[skey][sc] = *(const ushort8*)&src[sc];
      *(ushort8*)&Klds[skey][sc + 32] = *(const ushort8*)&src[sc + 32];
    }
    __syncthreads();
    f32x4 sacc[4];
#pragma unroll
    for (int st = 0; st < 4; ++st)
#pragma unroll
      for (int r = 0; r < 4; ++r) sacc[st][r] = 0.f;
#pragma unroll
    for (int st = 0; st < 4; ++st) {
      bf16x8 kf0 = ldb8(&Klds[st * 16 + j][g * 8]);
      bf16x8 kf1 = ldb8(&Klds[st * 16 + j][32 + g * 8]);
      sacc[st] = mfma16(qa0, kf0, sacc[st]);
      sacc[st] = mfma16(qa1, kf1, sacc[st]);
    }
    bool diag = (kt == qt);
#pragma unroll
    for (int r = 0; r < 4; ++r) {
      int qrow = qrow0 + r;
#pragma unroll
      for (int st = 0; st < 4; ++st) {
        float p = __expf(sacc[st][r]);
        if (diag) {
          int kc = kt * 64 + st * 16 + j;
          p = (kc > qrow) ? 0.f : p;
        }
        lpart[r] += p;
      }
    }
  }

  // deferred reduce over the 16 j-lanes
  float linv[4];
#pragma unroll
  for (int r = 0; r < 4; ++r) {
    float sum = lpart[r];
#pragma unroll
    for (int o = 1; o < 16; o <<= 1) sum += __shfl_xor(sum, o);
    linv[r] = 1.f / sum;
  }

  f32x4 oacc[4];
#pragma unroll
  for (int st = 0; st < 4; ++st)
#pragma unroll
    for (int r = 0; r < 4; ++r) oacc[st][r] = 0.f;

  int prow = l >> 2;        // P writeback: row 0..15
  int pch = l & 3;          // chunk base (8 keys per chunk)

  // ---- phase 2: P write + PV ----
  for (int kt = 0; kt < SEQ / 64; ++kt) {
    if (kt <= qt) {
      __syncthreads();
      {
        const unsigned short* src = &kb[(size_t)(kt * 64 + skey) * 64];
        *(ushort8*)&Klds[skey][sc] = *(const ushort8*)&src[sc];
        *(ushort8*)&Klds[skey][sc + 32] = *(const ushort8*)&src[sc + 32];
        const unsigned short* vsrc = &vb[(size_t)skey * SEQ + kt * 64];
        *(ushort8*)&Vlds[skey][sc] = *(const ushort8*)&vsrc[sc];
        *(ushort8*)&Vlds[skey][sc + 32] = *(const ushort8*)&vsrc[sc + 32];
      }
      __syncthreads();
      f32x4 sacc[4];
#pragma unroll
      for (int st = 0; st < 4; ++st)
#pragma unroll
        for (int r = 0; r < 4; ++r) sacc[st][r] = 0.f;
#pragma unroll
      for (int st = 0; st < 4; ++st) {
        bf16x8 kf0 = ldb8(&Klds[st * 16 + j][g * 8]);
        bf16x8 kf1 = ldb8(&Klds[st * 16 + j][32 + g * 8]);
        sacc[st] = mfma16(qa0, kf0, sacc[st]);
        sacc[st] = mfma16(qa1, kf1, sacc[st]);
      }
      bool diag = (kt == qt);
#pragma unroll
      for (int st = 0; st < 4; ++st) {
#pragma unroll
        for (int r = 0; r < 4; ++r) {
          int qrow = qrow0 + r;
          int kc = kt * 64 + st * 16 + j;
          float p = __expf(sacc[st][r]) * linv[r];
          if (diag) p = (kc > qrow) ? 0.f : p;
          Plds[w][g * 4 + r][st * 16 + j] = f2bf(p);
        }
      }
      // Plds[w] is wave-private: no barrier needed, lgkmcnt orders write->read.
      // vectorized P global write (bf16 -> f32), 128B per 4 lanes
#pragma unroll
      for (int it = 0; it < 2; ++it) {
        int ch = pch + it * 4;
        ushort8 pv = *(const ushort8*)&Plds[w][prow][ch * 8];
        float4 f0, f1;
        f0.x = bf2f(pv[0]); f0.y = bf2f(pv[1]); f0.z = bf2f(pv[2]); f0.w = bf2f(pv[3]);
        f1.x = bf2f(pv[4]); f1.y = bf2f(pv[5]); f1.z = bf2f(pv[6]); f1.w = bf2f(pv[7]);
        float* dst = &outrow[(size_t)(qt * 64 + w * 16 + prow) * SEQ + kt * 64 + ch * 8];
        ((float4*)dst)[0] = f0;
        ((float4*)dst)[1] = f1;
      }
      bf16x8 pa0 = ldb8(&Plds[w][j][g * 8]);
      bf16x8 pa1 = ldb8(&Plds[w][j][32 + g * 8]);
#pragma unroll
      for (int st = 0; st < 4; ++st) {
        bf16x8 vf0 = ldb8(&Vlds[st * 16 + j][g * 8]);
        bf16x8 vf1 = ldb8(&Vlds[st * 16 + j][32 + g * 8]);
        oacc[st] = mfma16(pa0, vf0, oacc[st]);
        oacc[st] = mfma16(pa1, vf1, oacc[st]);
      }
    } else {
      // fully-masked tile: softmax underflows to exact 0
      int row = qt * 64 + w * 16 + (l >> 2);
      int c0 = kt * 64 + (l & 3) * 16;
      float4 z = make_float4(0.f, 0.f, 0.f, 0.f);
      float4* zp = (float4*)&outrow[(size_t)row * SEQ + c0];
      zp[0] = z; zp[1] = z; zp[2] = z; zp[3] = z;
    }
  }

  // write O to [B][SEQ][DMODEL] bf16 intermediate
#pragma unroll
  for (int st = 0; st < 4; ++st)
#pragma unroll
    for (int r = 0; r < 4; ++r) {
      int qrow = qrow0 + r;
      int d = st * 16 + j;
      ointer[((size_t)b * SEQ + qrow) * DMODEL + h * 64 + d] = f2bf(oacc[st][r]);
    }
}

extern "C" void kernel_launch(void* const* d_in, const int* in_sizes, int n_in,
                              void* d_out, int out_size, void* d_ws, size_t ws_size,
                              hipStream_t stream) {
  const float* hidden = (const float*)d_in[0];   // [2,2048,1024]
  const float* w_attn = (const float*)d_in[1];   // [1024,3072]
  const float* b_attn = (const float*)d_in[2];   // [3072]
  const float* w_proj = (const float*)d_in[3];   // [1024,1024]
  const float* b_proj = (const float*)d_in[4];   // [1024]

  float* out_attn = (float*)d_out;                          // 4,194,304 f32
  float* out_w = out_attn + (size_t)MTOT * DMODEL;          // 134,217,728 f32

  char* ws = (char*)d_ws;
  unsigned short* hbf = (unsigned short*)(ws);              // [4096][1024] bf16; later reused as attn O
  unsigned short* w1T = (unsigned short*)(ws + 8388608);    // [3072][1024] bf16
  unsigned short* w2T = (unsigned short*)(ws + 14680064);   // [1024][1024] bf16
  unsigned short* qws = (unsigned short*)(ws + 16777216);   // [32][2048][64] bf16 (pre-scaled 1/8)
  unsigned short* kws = (unsigned short*)(ws + 25165824);   // [32][2048][64]
  unsigned short* vws = (unsigned short*)(ws + 33554432);   // [32][64][2048] (transposed)

  cast_kernel<<<4096, 256, 0, stream>>>(hidden, hbf);
  transpose_cast_kernel<<<dim3(96, 32), 256, 0, stream>>>(w_attn, w1T, 1024, 3072);
  transpose_cast_kernel<<<dim3(32, 32), 256, 0, stream>>>(w_proj, w2T, 1024, 1024);
  gemm128<0><<<dim3(32, 24), 256, 0, stream>>>(hbf, w1T, b_attn, nullptr, qws, kws, vws,
                                               MTOT, 3 * DMODEL, DMODEL);
  attn_kernel<<<dim3(32, 32), 256, 0, stream>>>(qws, kws, vws, out_w, hbf);
  gemm128<1><<<dim3(32, 8), 256, 0, stream>>>(hbf, w2T, b_proj, out_attn, nullptr, nullptr,
                                              nullptr, MTOT, DMODEL, DMODEL);
}

// Round 12
// 268.681 us; speedup vs baseline: 2.3536x; 1.0103x over previous
//
#include <hip/hip_runtime.h>

// GPT-2 attention block for MI355X (gfx950), bf16 MFMA everywhere, fp32 accum.
// Outputs: [attn_output 2*2048*1024 f32][attn_weights 2*16*2048*2048 f32]
// R12 = R3 structure + heavy/light interleaved qt mapping (per-CU balance under
// consecutive-co-residency): bx -> 31,0,30,1,... every 4-window sums to avg work.

typedef __bf16 bf16_t;
typedef bf16_t bf16x8 __attribute__((ext_vector_type(8)));
typedef float f32x4 __attribute__((ext_vector_type(4)));
typedef unsigned short ushort8 __attribute__((ext_vector_type(8)));
typedef unsigned short ushort4v __attribute__((ext_vector_type(4)));

#define SEQ 2048
#define DMODEL 1024
#define MTOT 4096  // B*SEQ

#define AS1 __attribute__((address_space(1)))
#define AS3 __attribute__((address_space(3)))

__device__ __forceinline__ unsigned short f2bf(float f) {
  return __builtin_bit_cast(unsigned short, (bf16_t)f);
}
__device__ __forceinline__ float bf2f(unsigned short u) {
  return __builtin_bit_cast(float, (unsigned)u << 16);
}
__device__ __forceinline__ bf16x8 ldb8(const unsigned short* p) {
  return __builtin_bit_cast(bf16x8, *(const ushort8*)p);
}
__device__ __forceinline__ f32x4 mfma16(bf16x8 a, bf16x8 b, f32x4 c) {
  return __builtin_amdgcn_mfma_f32_16x16x32_bf16(a, b, c, 0, 0, 0);
}
// async global->LDS, 16 bytes per lane. LDS dest must be wave-uniform-base + lane*16.
__device__ __forceinline__ void gload16(const unsigned short* g, unsigned short* l) {
  __builtin_amdgcn_global_load_lds((AS1 const void*)g, (AS3 void*)l, 16, 0, 0);
}

// ---------- cast f32 -> bf16 bits ----------
__global__ __launch_bounds__(256) void cast_kernel(const float* __restrict__ in,
                                                   unsigned short* __restrict__ out) {
  int i = blockIdx.x * 256 + threadIdx.x;
  float4 v = ((const float4*)in)[i];
  ushort4v o;
  o[0] = f2bf(v.x); o[1] = f2bf(v.y); o[2] = f2bf(v.z); o[3] = f2bf(v.w);
  ((ushort4v*)out)[i] = o;
}

// ---------- transpose + cast: in f32 [R][C] -> out bf16 [C][R] ----------
__global__ __launch_bounds__(256) void transpose_cast_kernel(const float* __restrict__ in,
                                                             unsigned short* __restrict__ out,
                                                             int R, int C) {
  __shared__ float tile[32][33];
  int c0 = blockIdx.x * 32, r0 = blockIdx.y * 32;
  int tx = threadIdx.x & 31, ty = threadIdx.x >> 5;
#pragma unroll
  for (int i = 0; i < 4; ++i)
    tile[ty + i * 8][tx] = in[(size_t)(r0 + ty + i * 8) * C + c0 + tx];
  __syncthreads();
#pragma unroll
  for (int i = 0; i < 4; ++i)
    out[(size_t)(c0 + ty + i * 8) * R + r0 + tx] = f2bf(tile[tx][ty + i * 8]);
}

// ---------- m97-structure bf16 GEMM: C[M][N] = A[M][K]*BT[N][K]^T + bias ----------
template <int EPI>
__global__ __launch_bounds__(256) void gemm128(
    const unsigned short* __restrict__ A, const unsigned short* __restrict__ BT,
    const float* __restrict__ bias, float* __restrict__ outF,
    unsigned short* __restrict__ qws, unsigned short* __restrict__ kws,
    unsigned short* __restrict__ vws, int M, int N, int K) {
  __shared__ unsigned short Alds[128 * 32];
  __shared__ unsigned short Blds[128 * 32];
  int m0 = blockIdx.x * 128, n0 = blockIdx.y * 128;
  int t = threadIdx.x;
  int l = t & 63, j = l & 15, g = l >> 4;
  int w = t >> 6, wr = w >> 1, wc = w & 1;

  f32x4 acc[4][4];
#pragma unroll
  for (int mi = 0; mi < 4; ++mi)
#pragma unroll
    for (int st = 0; st < 4; ++st)
#pragma unroll
      for (int r = 0; r < 4; ++r) acc[mi][st][r] = 0.f;

  int srow = t >> 2;          // 0..63
  int scol = (t & 3) * 8;     // 0,8,16,24
  const unsigned short* aB0 = A + (size_t)(m0 + srow) * K + scol;
  const unsigned short* aB1 = aB0 + (size_t)64 * K;
  const unsigned short* bB0 = BT + (size_t)(n0 + srow) * K + scol;
  const unsigned short* bB1 = bB0 + (size_t)64 * K;
  unsigned short* aL0 = &Alds[srow * 32 + scol];
  unsigned short* aL1 = aL0 + 64 * 32;
  unsigned short* bL0 = &Blds[srow * 32 + scol];
  unsigned short* bL1 = bL0 + 64 * 32;

  for (int k0 = 0; k0 < K; k0 += 32) {
    __syncthreads();
    gload16(aB0 + k0, aL0);
    gload16(aB1 + k0, aL1);
    gload16(bB0 + k0, bL0);
    gload16(bB1 + k0, bL1);
    __syncthreads();
    bf16x8 af[4], bfr[4];
#pragma unroll
    for (int mi = 0; mi < 4; ++mi) af[mi] = ldb8(&Alds[(wr * 64 + mi * 16 + j) * 32 + g * 8]);
#pragma unroll
    for (int st = 0; st < 4; ++st) bfr[st] = ldb8(&Blds[(wc * 64 + st * 16 + j) * 32 + g * 8]);
#pragma unroll
    for (int mi = 0; mi < 4; ++mi)
#pragma unroll
      for (int st = 0; st < 4; ++st) acc[mi][st] = mfma16(af[mi], bfr[st], acc[mi][st]);
  }

#pragma unroll
  for (int st = 0; st < 4; ++st) {
    int n = n0 + wc * 64 + st * 16 + j;
    float bv = bias[n];
#pragma unroll
    for (int mi = 0; mi < 4; ++mi)
#pragma unroll
      for (int r = 0; r < 4; ++r) {
        int m = m0 + wr * 64 + mi * 16 + g * 4 + r;
        float val = acc[mi][st][r] + bv;
        if (EPI == 1) {
          outF[(size_t)m * N + n] = val;
        } else {
          int region = n >> 10;          // 0=q 1=k 2=v
          int h = (n & 1023) >> 6;
          int d = n & 63;
          int bb = m >> 11, s = m & 2047;
          int bh = bb * 16 + h;
          if (region == 0) qws[(((size_t)bh) * SEQ + s) * 64 + d] = f2bf(val * 0.125f);
          else if (region == 1) kws[(((size_t)bh) * SEQ + s) * 64 + d] = f2bf(val);
          else vws[(((size_t)bh) * 64 + d) * SEQ + s] = f2bf(val);  // transposed
        }
      }
  }
}

// ---------- fused causal attention (R3 structure, interleaved qt mapping) ----------
// grid (32 q-tiles, 32 b*h); 4 waves/block, wave owns 16 q-rows.
// qt map: bx -> 31,0,30,1,...  Every 4 consecutive bx (co-resident on a CU under
// linear dispatch) carry exactly the average work -> balanced per-CU makespan.
__global__ __launch_bounds__(256) void attn_kernel(
    const unsigned short* __restrict__ qg, const unsigned short* __restrict__ kg,
    const unsigned short* __restrict__ vg, float* __restrict__ outw,
    unsigned short* __restrict__ ointer) {
  __shared__ unsigned short Klds[64][72];       // [key][d]
  __shared__ unsigned short Vlds[64][72];       // [d][key] (transposed in global)
  __shared__ unsigned short Plds[4][16][72];    // per-wave P tile [qrow][key], bf16

  int v = blockIdx.x;
  int qt = (v & 1) ? ((v - 1) >> 1) : (31 - (v >> 1));   // R12: heavy/light interleave
  int bh = blockIdx.y;
  int b = bh >> 4, h = bh & 15;
  int t = threadIdx.x;
  int w = t >> 6, l = t & 63, j = l & 15, g = l >> 4;

  const unsigned short* qb = qg + (size_t)bh * SEQ * 64;
  const unsigned short* kb = kg + (size_t)bh * SEQ * 64;
  const unsigned short* vb = vg + (size_t)bh * SEQ * 64;  // [64][SEQ]
  float* outrow = outw + (size_t)bh * SEQ * SEQ;

  int qr_a = qt * 64 + w * 16 + j;  // A-fragment row
  bf16x8 qa0 = ldb8(&qb[(size_t)qr_a * 64 + g * 8]);
  bf16x8 qa1 = ldb8(&qb[(size_t)qr_a * 64 + 32 + g * 8]);

  int qrow0 = qt * 64 + w * 16 + g * 4;  // D rows = qrow0 + r

  float lpart[4] = {0.f, 0.f, 0.f, 0.f};

  int skey = t >> 2;        // staging row (key for K, d for V)
  int sc = (t & 3) * 8;     // staging col chunk

  // ---- phase 1: per-lane partial sums of exp(s) ----
  for (int kt = 0; kt <= qt; ++kt) {
    __syncthreads();
    {
      const unsigned short* src = &kb[(size_t)(kt * 64 + skey) * 64];
      *(ushort8*)&Klds[skey][sc] = *(const ushort8*)&src[sc];
      *(ushort8*)&Klds[skey][sc + 32] = *(const ushort8*)&src[sc + 32];
    }
    __syncthreads();
    f32x4 sacc[4];
#pragma unroll
    for (int st = 0; st < 4; ++st)
#pragma unroll
      for (int r = 0; r < 4; ++r) sacc[st][r] = 0.f;
#pragma unroll
    for (int st = 0; st < 4; ++st) {
      bf16x8 kf0 = ldb8(&Klds[st * 16 + j][g * 8]);
      bf16x8 kf1 = ldb8(&Klds[st * 16 + j][32 + g * 8]);
      sacc[st] = mfma16(qa0, kf0, sacc[st]);
      sacc[st] = mfma16(qa1, kf1, sacc[st]);
    }
    bool diag = (kt == qt);
#pragma unroll
    for (int r = 0; r < 4; ++r) {
      int qrow = qrow0 + r;
#pragma unroll
      for (int st = 0; st < 4; ++st) {
        float p = __expf(sacc[st][r]);
        if (diag) {
          int kc = kt * 64 + st * 16 + j;
          p = (kc > qrow) ? 0.f : p;
        }
        lpart[r] += p;
      }
    }
  }

  // deferred reduce over the 16 j-lanes
  float linv[4];
#pragma unroll
  for (int r = 0; r < 4; ++r) {
    float sum = lpart[r];
#pragma unroll
    for (int o = 1; o < 16; o <<= 1) sum += __shfl_xor(sum, o);
    linv[r] = 1.f / sum;
  }

  f32x4 oacc[4];
#pragma unroll
  for (int st = 0; st < 4; ++st)
#pragma unroll
    for (int r = 0; r < 4; ++r) oacc[st][r] = 0.f;

  int prow = l >> 2;        // P writeback: row 0..15
  int pch = l & 3;          // chunk base (8 keys per chunk)

  // ---- phase 2: P write + PV ----
  for (int kt = 0; kt < SEQ / 64; ++kt) {
    if (kt <= qt) {
      __syncthreads();
      {
        const unsigned short* src = &kb[(size_t)(kt * 64 + skey) * 64];
        *(ushort8*)&Klds[skey][sc] = *(const ushort8*)&src[sc];
        *(ushort8*)&Klds[skey][sc + 32] = *(const ushort8*)&src[sc + 32];
        const unsigned short* vsrc = &vb[(size_t)skey * SEQ + kt * 64];
        *(ushort8*)&Vlds[skey][sc] = *(const ushort8*)&vsrc[sc];
        *(ushort8*)&Vlds[skey][sc + 32] = *(const ushort8*)&vsrc[sc + 32];
      }
      __syncthreads();
      f32x4 sacc[4];
#pragma unroll
      for (int st = 0; st < 4; ++st)
#pragma unroll
        for (int r = 0; r < 4; ++r) sacc[st][r] = 0.f;
#pragma unroll
      for (int st = 0; st < 4; ++st) {
        bf16x8 kf0 = ldb8(&Klds[st * 16 + j][g * 8]);
        bf16x8 kf1 = ldb8(&Klds[st * 16 + j][32 + g * 8]);
        sacc[st] = mfma16(qa0, kf0, sacc[st]);
        sacc[st] = mfma16(qa1, kf1, sacc[st]);
      }
      bool diag = (kt == qt);
#pragma unroll
      for (int st = 0; st < 4; ++st) {
#pragma unroll
        for (int r = 0; r < 4; ++r) {
          int qrow = qrow0 + r;
          int kc = kt * 64 + st * 16 + j;
          float p = __expf(sacc[st][r]) * linv[r];
          if (diag) p = (kc > qrow) ? 0.f : p;
          Plds[w][g * 4 + r][st * 16 + j] = f2bf(p);
        }
      }
      // Plds[w] is wave-private: no barrier needed, lgkmcnt orders write->read.
      // vectorized P global write (bf16 -> f32), 128B per 4 lanes
#pragma unroll
      for (int it = 0; it < 2; ++it) {
        int ch = pch + it * 4;
        ushort8 pv = *(const ushort8*)&Plds[w][prow][ch * 8];
        float4 f0, f1;
        f0.x = bf2f(pv[0]); f0.y = bf2f(pv[1]); f0.z = bf2f(pv[2]); f0.w = bf2f(pv[3]);
        f1.x = bf2f(pv[4]); f1.y = bf2f(pv[5]); f1.z = bf2f(pv[6]); f1.w = bf2f(pv[7]);
        float* dst = &outrow[(size_t)(qt * 64 + w * 16 + prow) * SEQ + kt * 64 + ch * 8];
        ((float4*)dst)[0] = f0;
        ((float4*)dst)[1] = f1;
      }
      bf16x8 pa0 = ldb8(&Plds[w][j][g * 8]);
      bf16x8 pa1 = ldb8(&Plds[w][j][32 + g * 8]);
#pragma unroll
      for (int st = 0; st < 4; ++st) {
        bf16x8 vf0 = ldb8(&Vlds[st * 16 + j][g * 8]);
        bf16x8 vf1 = ldb8(&Vlds[st * 16 + j][32 + g * 8]);
        oacc[st] = mfma16(pa0, vf0, oacc[st]);
        oacc[st] = mfma16(pa1, vf1, oacc[st]);
      }
    } else {
      // fully-masked tile: softmax underflows to exact 0
      int row = qt * 64 + w * 16 + (l >> 2);
      int c0 = kt * 64 + (l & 3) * 16;
      float4 z = make_float4(0.f, 0.f, 0.f, 0.f);
      float4* zp = (float4*)&outrow[(size_t)row * SEQ + c0];
      zp[0] = z; zp[1] = z; zp[2] = z; zp[3] = z;
    }
  }

  // write O to [B][SEQ][DMODEL] bf16 intermediate
#pragma unroll
  for (int st = 0; st < 4; ++st)
#pragma unroll
    for (int r = 0; r < 4; ++r) {
      int qrow = qrow0 + r;
      int d = st * 16 + j;
      ointer[((size_t)b * SEQ + qrow) * DMODEL + h * 64 + d] = f2bf(oacc[st][r]);
    }
}

extern "C" void kernel_launch(void* const* d_in, const int* in_sizes, int n_in,
                              void* d_out, int out_size, void* d_ws, size_t ws_size,
                              hipStream_t stream) {
  const float* hidden = (const float*)d_in[0];   // [2,2048,1024]
  const float* w_attn = (const float*)d_in[1];   // [1024,3072]
  const float* b_attn = (const float*)d_in[2];   // [3072]
  const float* w_proj = (const float*)d_in[3];   // [1024,1024]
  const float* b_proj = (const float*)d_in[4];   // [1024]

  float* out_attn = (float*)d_out;                          // 4,194,304 f32
  float* out_w = out_attn + (size_t)MTOT * DMODEL;          // 134,217,728 f32

  char* ws = (char*)d_ws;
  unsigned short* hbf = (unsigned short*)(ws);              // [4096][1024] bf16; later reused as attn O
  unsigned short* w1T = (unsigned short*)(ws + 8388608);    // [3072][1024] bf16
  unsigned short* w2T = (unsigned short*)(ws + 14680064);   // [1024][1024] bf16
  unsigned short* qws = (unsigned short*)(ws + 16777216);   // [32][2048][64] bf16 (pre-scaled 1/8)
  unsigned short* kws = (unsigned short*)(ws + 25165824);   // [32][2048][64]
  unsigned short* vws = (unsigned short*)(ws + 33554432);   // [32][64][2048] (transposed)

  cast_kernel<<<4096, 256, 0, stream>>>(hidden, hbf);
  transpose_cast_kernel<<<dim3(96, 32), 256, 0, stream>>>(w_attn, w1T, 1024, 3072);
  transpose_cast_kernel<<<dim3(32, 32), 256, 0, stream>>>(w_proj, w2T, 1024, 1024);
  gemm128<0><<<dim3(32, 24), 256, 0, stream>>>(hbf, w1T, b_attn, nullptr, qws, kws, vws,
                                               MTOT, 3 * DMODEL, DMODEL);
  attn_kernel<<<dim3(32, 32), 256, 0, stream>>>(qws, kws, vws, out_w, hbf);
  gemm128<1><<<dim3(32, 8), 256, 0, stream>>>(hbf, w2T, b_proj, out_attn, nullptr, nullptr,
                                              nullptr, MTOT, DMODEL, DMODEL);
}

// Round 13
// 267.449 us; speedup vs baseline: 2.3645x; 1.0046x over previous
//
#include <hip/hip_runtime.h>

// GPT-2 attention block for MI355X (gfx950), bf16 MFMA everywhere, fp32 accum.
// Outputs: [attn_output 2*2048*1024 f32][attn_weights 2*16*2048*2048 f32]
// R13 = R12 + attn staging via single-buffered global_load_lds (m97-style)
// with XOR-swizzled linear LDS tiles (swizzle on global source + read addr).

typedef __bf16 bf16_t;
typedef bf16_t bf16x8 __attribute__((ext_vector_type(8)));
typedef float f32x4 __attribute__((ext_vector_type(4)));
typedef unsigned short ushort8 __attribute__((ext_vector_type(8)));
typedef unsigned short ushort4v __attribute__((ext_vector_type(4)));

#define SEQ 2048
#define DMODEL 1024
#define MTOT 4096  // B*SEQ

#define AS1 __attribute__((address_space(1)))
#define AS3 __attribute__((address_space(3)))

__device__ __forceinline__ unsigned short f2bf(float f) {
  return __builtin_bit_cast(unsigned short, (bf16_t)f);
}
__device__ __forceinline__ float bf2f(unsigned short u) {
  return __builtin_bit_cast(float, (unsigned)u << 16);
}
__device__ __forceinline__ bf16x8 ldb8(const unsigned short* p) {
  return __builtin_bit_cast(bf16x8, *(const ushort8*)p);
}
__device__ __forceinline__ f32x4 mfma16(bf16x8 a, bf16x8 b, f32x4 c) {
  return __builtin_amdgcn_mfma_f32_16x16x32_bf16(a, b, c, 0, 0, 0);
}
// async global->LDS, 16 bytes per lane. LDS dest must be wave-uniform-base + lane*16.
__device__ __forceinline__ void gload16(const unsigned short* g, unsigned short* l) {
  __builtin_amdgcn_global_load_lds((AS1 const void*)g, (AS3 void*)l, 16, 0, 0);
}

// ---------- cast f32 -> bf16 bits ----------
__global__ __launch_bounds__(256) void cast_kernel(const float* __restrict__ in,
                                                   unsigned short* __restrict__ out) {
  int i = blockIdx.x * 256 + threadIdx.x;
  float4 v = ((const float4*)in)[i];
  ushort4v o;
  o[0] = f2bf(v.x); o[1] = f2bf(v.y); o[2] = f2bf(v.z); o[3] = f2bf(v.w);
  ((ushort4v*)out)[i] = o;
}

// ---------- transpose + cast: in f32 [R][C] -> out bf16 [C][R] ----------
__global__ __launch_bounds__(256) void transpose_cast_kernel(const float* __restrict__ in,
                                                             unsigned short* __restrict__ out,
                                                             int R, int C) {
  __shared__ float tile[32][33];
  int c0 = blockIdx.x * 32, r0 = blockIdx.y * 32;
  int tx = threadIdx.x & 31, ty = threadIdx.x >> 5;
#pragma unroll
  for (int i = 0; i < 4; ++i)
    tile[ty + i * 8][tx] = in[(size_t)(r0 + ty + i * 8) * C + c0 + tx];
  __syncthreads();
#pragma unroll
  for (int i = 0; i < 4; ++i)
    out[(size_t)(c0 + ty + i * 8) * R + r0 + tx] = f2bf(tile[tx][ty + i * 8]);
}

// ---------- m97-structure bf16 GEMM: C[M][N] = A[M][K]*BT[N][K]^T + bias ----------
template <int EPI>
__global__ __launch_bounds__(256) void gemm128(
    const unsigned short* __restrict__ A, const unsigned short* __restrict__ BT,
    const float* __restrict__ bias, float* __restrict__ outF,
    unsigned short* __restrict__ qws, unsigned short* __restrict__ kws,
    unsigned short* __restrict__ vws, int M, int N, int K) {
  __shared__ unsigned short Alds[128 * 32];
  __shared__ unsigned short Blds[128 * 32];
  int m0 = blockIdx.x * 128, n0 = blockIdx.y * 128;
  int t = threadIdx.x;
  int l = t & 63, j = l & 15, g = l >> 4;
  int w = t >> 6, wr = w >> 1, wc = w & 1;

  f32x4 acc[4][4];
#pragma unroll
  for (int mi = 0; mi < 4; ++mi)
#pragma unroll
    for (int st = 0; st < 4; ++st)
#pragma unroll
      for (int r = 0; r < 4; ++r) acc[mi][st][r] = 0.f;

  int srow = t >> 2;          // 0..63
  int scol = (t & 3) * 8;     // 0,8,16,24
  const unsigned short* aB0 = A + (size_t)(m0 + srow) * K + scol;
  const unsigned short* aB1 = aB0 + (size_t)64 * K;
  const unsigned short* bB0 = BT + (size_t)(n0 + srow) * K + scol;
  const unsigned short* bB1 = bB0 + (size_t)64 * K;
  unsigned short* aL0 = &Alds[srow * 32 + scol];
  unsigned short* aL1 = aL0 + 64 * 32;
  unsigned short* bL0 = &Blds[srow * 32 + scol];
  unsigned short* bL1 = bL0 + 64 * 32;

  for (int k0 = 0; k0 < K; k0 += 32) {
    __syncthreads();
    gload16(aB0 + k0, aL0);
    gload16(aB1 + k0, aL1);
    gload16(bB0 + k0, bL0);
    gload16(bB1 + k0, bL1);
    __syncthreads();
    bf16x8 af[4], bfr[4];
#pragma unroll
    for (int mi = 0; mi < 4; ++mi) af[mi] = ldb8(&Alds[(wr * 64 + mi * 16 + j) * 32 + g * 8]);
#pragma unroll
    for (int st = 0; st < 4; ++st) bfr[st] = ldb8(&Blds[(wc * 64 + st * 16 + j) * 32 + g * 8]);
#pragma unroll
    for (int mi = 0; mi < 4; ++mi)
#pragma unroll
      for (int st = 0; st < 4; ++st) acc[mi][st] = mfma16(af[mi], bfr[st], acc[mi][st]);
  }

#pragma unroll
  for (int st = 0; st < 4; ++st) {
    int n = n0 + wc * 64 + st * 16 + j;
    float bv = bias[n];
#pragma unroll
    for (int mi = 0; mi < 4; ++mi)
#pragma unroll
      for (int r = 0; r < 4; ++r) {
        int m = m0 + wr * 64 + mi * 16 + g * 4 + r;
        float val = acc[mi][st][r] + bv;
        if (EPI == 1) {
          outF[(size_t)m * N + n] = val;
        } else {
          int region = n >> 10;          // 0=q 1=k 2=v
          int h = (n & 1023) >> 6;
          int d = n & 63;
          int bb = m >> 11, s = m & 2047;
          int bh = bb * 16 + h;
          if (region == 0) qws[(((size_t)bh) * SEQ + s) * 64 + d] = f2bf(val * 0.125f);
          else if (region == 1) kws[(((size_t)bh) * SEQ + s) * 64 + d] = f2bf(val);
          else vws[(((size_t)bh) * 64 + d) * SEQ + s] = f2bf(val);  // transposed
        }
      }
  }
}

// ---------- fused causal attention (R12 + global_load_lds staging) ----------
// grid (32 q-tiles interleaved heavy/light, 32 b*h); 4 waves, wave owns 16 q-rows.
// K/V tiles: linear [64][64] LDS, 16B-slot XOR swizzle (slot ^= row&7) applied to
// global source at staging AND to the ds_read address (both-sides involution).
__global__ __launch_bounds__(256) void attn_kernel(
    const unsigned short* __restrict__ qg, const unsigned short* __restrict__ kg,
    const unsigned short* __restrict__ vg, float* __restrict__ outw,
    unsigned short* __restrict__ ointer) {
  __shared__ unsigned short Klds[64 * 64];      // [key][d], swizzled
  __shared__ unsigned short Vlds[64 * 64];      // [d][key], swizzled
  __shared__ unsigned short Plds[4][16][72];    // per-wave P tile, bf16 (VALU-written)

  int v = blockIdx.x;
  int qt = (v & 1) ? ((v - 1) >> 1) : (31 - (v >> 1));   // heavy/light interleave
  int bh = blockIdx.y;
  int b = bh >> 4, h = bh & 15;
  int t = threadIdx.x;
  int w = t >> 6, l = t & 63, j = l & 15, g = l >> 4;

  const unsigned short* qb = qg + (size_t)bh * SEQ * 64;
  const unsigned short* kb = kg + (size_t)bh * SEQ * 64;
  const unsigned short* vb = vg + (size_t)bh * SEQ * 64;  // [64][SEQ]
  float* outrow = outw + (size_t)bh * SEQ * SEQ;

  int qr_a = qt * 64 + w * 16 + j;  // A-fragment row
  bf16x8 qa0 = ldb8(&qb[(size_t)qr_a * 64 + g * 8]);
  bf16x8 qa1 = ldb8(&qb[(size_t)qr_a * 64 + 32 + g * 8]);

  int qrow0 = qt * 64 + w * 16 + g * 4;  // D rows = qrow0 + r

  // staging: thread t owns 16B slot t of each 8KB tile half (rows 0-31 / 32-63)
  int srow = t >> 3;                         // 0..31
  int swz8 = ((t & 7) ^ (srow & 7)) * 8;     // swizzled source chunk
  const unsigned short* ksrc0 = kb + srow * 64 + swz8;            // + kt*4096
  const unsigned short* ksrc1 = ksrc0 + 32 * 64;
  const unsigned short* vsrc0 = vb + (size_t)srow * SEQ + swz8;   // + kt*64
  const unsigned short* vsrc1 = vsrc0 + (size_t)32 * SEQ;
  unsigned short* kd0 = &Klds[t * 8];
  unsigned short* kd1 = kd0 + 2048;
  unsigned short* vd0 = &Vlds[t * 8];
  unsigned short* vd1 = vd0 + 2048;

  // fragment read bases (swizzled): row j, chunks g and 4+g
  int rb0 = j * 64 + ((g ^ (j & 7)) * 8);
  int rb1 = j * 64 + (((4 + g) ^ (j & 7)) * 8);

  float lpart[4] = {0.f, 0.f, 0.f, 0.f};

  // ---- phase 1: per-lane partial sums of exp(s) ----
  for (int kt = 0; kt <= qt; ++kt) {
    __syncthreads();      // prior tile consumed
    gload16(ksrc0 + kt * 4096, kd0);
    gload16(ksrc1 + kt * 4096, kd1);
    __syncthreads();      // staged (vmcnt drained before barrier)
    f32x4 sacc[4];
#pragma unroll
    for (int st = 0; st < 4; ++st)
#pragma unroll
      for (int r = 0; r < 4; ++r) sacc[st][r] = 0.f;
#pragma unroll
    for (int st = 0; st < 4; ++st) {
      bf16x8 kf0 = ldb8(&Klds[st * 1024 + rb0]);
      bf16x8 kf1 = ldb8(&Klds[st * 1024 + rb1]);
      sacc[st] = mfma16(qa0, kf0, sacc[st]);
      sacc[st] = mfma16(qa1, kf1, sacc[st]);
    }
    bool diag = (kt == qt);
#pragma unroll
    for (int r = 0; r < 4; ++r) {
      int qrow = qrow0 + r;
#pragma unroll
      for (int st = 0; st < 4; ++st) {
        float p = __expf(sacc[st][r]);
        if (diag) {
          int kc = kt * 64 + st * 16 + j;
          p = (kc > qrow) ? 0.f : p;
        }
        lpart[r] += p;
      }
    }
  }

  // deferred reduce over the 16 j-lanes
  float linv[4];
#pragma unroll
  for (int r = 0; r < 4; ++r) {
    float sum = lpart[r];
#pragma unroll
    for (int o = 1; o < 16; o <<= 1) sum += __shfl_xor(sum, o);
    linv[r] = 1.f / sum;
  }

  f32x4 oacc[4];
#pragma unroll
  for (int st = 0; st < 4; ++st)
#pragma unroll
    for (int r = 0; r < 4; ++r) oacc[st][r] = 0.f;

  int prow = l >> 2;        // P writeback: row 0..15
  int pch = l & 3;          // chunk base (8 keys per chunk)

  // ---- phase 2: P write + PV ----
  for (int kt = 0; kt < SEQ / 64; ++kt) {
    if (kt <= qt) {
      __syncthreads();
      gload16(ksrc0 + kt * 4096, kd0);
      gload16(ksrc1 + kt * 4096, kd1);
      gload16(vsrc0 + kt * 64, vd0);
      gload16(vsrc1 + kt * 64, vd1);
      __syncthreads();
      f32x4 sacc[4];
#pragma unroll
      for (int st = 0; st < 4; ++st)
#pragma unroll
        for (int r = 0; r < 4; ++r) sacc[st][r] = 0.f;
#pragma unroll
      for (int st = 0; st < 4; ++st) {
        bf16x8 kf0 = ldb8(&Klds[st * 1024 + rb0]);
        bf16x8 kf1 = ldb8(&Klds[st * 1024 + rb1]);
        sacc[st] = mfma16(qa0, kf0, sacc[st]);
        sacc[st] = mfma16(qa1, kf1, sacc[st]);
      }
      bool diag = (kt == qt);
#pragma unroll
      for (int st = 0; st < 4; ++st) {
#pragma unroll
        for (int r = 0; r < 4; ++r) {
          int qrow = qrow0 + r;
          int kc = kt * 64 + st * 16 + j;
          float p = __expf(sacc[st][r]) * linv[r];
          if (diag) p = (kc > qrow) ? 0.f : p;
          Plds[w][g * 4 + r][st * 16 + j] = f2bf(p);
        }
      }
      // Plds[w] wave-private: lgkmcnt orders write->read, no barrier.
      // vectorized P global write (bf16 -> f32), 128B per 4 lanes
#pragma unroll
      for (int it = 0; it < 2; ++it) {
        int ch = pch + it * 4;
        ushort8 pv = *(const ushort8*)&Plds[w][prow][ch * 8];
        float4 f0, f1;
        f0.x = bf2f(pv[0]); f0.y = bf2f(pv[1]); f0.z = bf2f(pv[2]); f0.w = bf2f(pv[3]);
        f1.x = bf2f(pv[4]); f1.y = bf2f(pv[5]); f1.z = bf2f(pv[6]); f1.w = bf2f(pv[7]);
        float* dst = &outrow[(size_t)(qt * 64 + w * 16 + prow) * SEQ + kt * 64 + ch * 8];
        ((float4*)dst)[0] = f0;
        ((float4*)dst)[1] = f1;
      }
      bf16x8 pa0 = ldb8(&Plds[w][j][g * 8]);
      bf16x8 pa1 = ldb8(&Plds[w][j][32 + g * 8]);
#pragma unroll
      for (int st = 0; st < 4; ++st) {
        bf16x8 vf0 = ldb8(&Vlds[st * 1024 + rb0]);
        bf16x8 vf1 = ldb8(&Vlds[st * 1024 + rb1]);
        oacc[st] = mfma16(pa0, vf0, oacc[st]);
        oacc[st] = mfma16(pa1, vf1, oacc[st]);
      }
    } else {
      // fully-masked tile: softmax underflows to exact 0
      int row = qt * 64 + w * 16 + (l >> 2);
      int c0 = kt * 64 + (l & 3) * 16;
      float4 z = make_float4(0.f, 0.f, 0.f, 0.f);
      float4* zp = (float4*)&outrow[(size_t)row * SEQ + c0];
      zp[0] = z; zp[1] = z; zp[2] = z; zp[3] = z;
    }
  }

  // write O to [B][SEQ][DMODEL] bf16 intermediate
#pragma unroll
  for (int st = 0; st < 4; ++st)
#pragma unroll
    for (int r = 0; r < 4; ++r) {
      int qrow = qrow0 + r;
      int d = st * 16 + j;
      ointer[((size_t)b * SEQ + qrow) * DMODEL + h * 64 + d] = f2bf(oacc[st][r]);
    }
}

extern "C" void kernel_launch(void* const* d_in, const int* in_sizes, int n_in,
                              void* d_out, int out_size, void* d_ws, size_t ws_size,
                              hipStream_t stream) {
  const float* hidden = (const float*)d_in[0];   // [2,2048,1024]
  const float* w_attn = (const float*)d_in[1];   // [1024,3072]
  const float* b_attn = (const float*)d_in[2];   // [3072]
  const float* w_proj = (const float*)d_in[3];   // [1024,1024]
  const float* b_proj = (const float*)d_in[4];   // [1024]

  float* out_attn = (float*)d_out;                          // 4,194,304 f32
  float* out_w = out_attn + (size_t)MTOT * DMODEL;          // 134,217,728 f32

  char* ws = (char*)d_ws;
  unsigned short* hbf = (unsigned short*)(ws);              // [4096][1024] bf16; later reused as attn O
  unsigned short* w1T = (unsigned short*)(ws + 8388608);    // [3072][1024] bf16
  unsigned short* w2T = (unsigned short*)(ws + 14680064);   // [1024][1024] bf16
  unsigned short* qws = (unsigned short*)(ws + 16777216);   // [32][2048][64] bf16 (pre-scaled 1/8)
  unsigned short* kws = (unsigned short*)(ws + 25165824);   // [32][2048][64]
  unsigned short* vws = (unsigned short*)(ws + 33554432);   // [32][64][2048] (transposed)

  cast_kernel<<<4096, 256, 0, stream>>>(hidden, hbf);
  transpose_cast_kernel<<<dim3(96, 32), 256, 0, stream>>>(w_attn, w1T, 1024, 3072);
  transpose_cast_kernel<<<dim3(32, 32), 256, 0, stream>>>(w_proj, w2T, 1024, 1024);
  gemm128<0><<<dim3(32, 24), 256, 0, stream>>>(hbf, w1T, b_attn, nullptr, qws, kws, vws,
                                               MTOT, 3 * DMODEL, DMODEL);
  attn_kernel<<<dim3(32, 32), 256, 0, stream>>>(qws, kws, vws, out_w, hbf);
  gemm128<1><<<dim3(32, 8), 256, 0, stream>>>(hbf, w2T, b_proj, out_attn, nullptr, nullptr,
                                              nullptr, MTOT, DMODEL, DMODEL);
}